// Round 2
// baseline (996.810 us; speedup 1.0000x reference)
//
#include <hip/hip_runtime.h>
#include <math.h>

// ---------------------------------------------------------------------------
// SheafGNN forward, fp32.
// Pipeline: h0 = x@Win+b; 2x [pq = h@W1packed; edge kernel -> atomic agg;
//           h = elu(h - eps*agg)]; out = h@Wout+b.
// Key algebraic restructure: concat([x_row,x_col])@w1 == p[row]+q[col] with
// p,q per-NODE GEMMs (16x fewer FLOPs than per-edge).
// Edge kernel: one edge per wave64, all exchange via __shfl (no LDS/barriers).
// msg[k] = M1 @ x_col[k] - M2 @ x_row[k],  M1 = Fu^T Fu, M2 = Fu^T Fv,
// Fu,Fv = expm(antisym 4x4) via scaling-squaring + Taylor(8).
// NOTE: harness delivers integer inputs as int32 (edge_index -> const int*).
// ---------------------------------------------------------------------------

__global__ void __launch_bounds__(256) k_pack_w1(const float* __restrict__ w1,
                                                 float* __restrict__ Wp) {
  int t = blockIdx.x * 256 + threadIdx.x;
  if (t >= 128 * 128) return;
  int i = t >> 7, o = t & 127;
  Wp[t] = (o < 64) ? w1[i * 64 + o] : w1[(128 + i) * 64 + (o - 64)];
}

// C(N x P) = A(N x 128) @ W(128 x P) + bias; P is 64 or 128, tile 64x64.
__global__ void __launch_bounds__(256) k_gemm128(const float* __restrict__ A,
    const float* __restrict__ W, const float* __restrict__ bias,
    float* __restrict__ C, int N, int P) {
  __shared__ float As[128 * 65];  // [k][node], stride 65 breaks bank conflicts
  int t = threadIdx.x;
  int nb = blockIdx.x << 6, cb = blockIdx.y << 6;
#pragma unroll
  for (int i = 0; i < 32; ++i) {
    int idx = (i << 8) + t;
    int node = idx >> 7, k = idx & 127;
    float v = 0.f;
    if (nb + node < N) v = A[(size_t)(nb + node) * 128 + k];
    As[k * 65 + node] = v;
  }
  __syncthreads();
  int tx = t & 15, ty = t >> 4;
  int c0 = cb + (tx << 2);
  int n0 = ty << 2;
  float acc[4][4] = {};
  for (int k = 0; k < 128; ++k) {
    float4 wv = *(const float4*)(W + (size_t)k * P + c0);
    float a0 = As[k * 65 + n0 + 0];
    float a1 = As[k * 65 + n0 + 1];
    float a2 = As[k * 65 + n0 + 2];
    float a3 = As[k * 65 + n0 + 3];
    acc[0][0] = fmaf(a0, wv.x, acc[0][0]);
    acc[0][1] = fmaf(a0, wv.y, acc[0][1]);
    acc[0][2] = fmaf(a0, wv.z, acc[0][2]);
    acc[0][3] = fmaf(a0, wv.w, acc[0][3]);
    acc[1][0] = fmaf(a1, wv.x, acc[1][0]);
    acc[1][1] = fmaf(a1, wv.y, acc[1][1]);
    acc[1][2] = fmaf(a1, wv.z, acc[1][2]);
    acc[1][3] = fmaf(a1, wv.w, acc[1][3]);
    acc[2][0] = fmaf(a2, wv.x, acc[2][0]);
    acc[2][1] = fmaf(a2, wv.y, acc[2][1]);
    acc[2][2] = fmaf(a2, wv.z, acc[2][2]);
    acc[2][3] = fmaf(a2, wv.w, acc[2][3]);
    acc[3][0] = fmaf(a3, wv.x, acc[3][0]);
    acc[3][1] = fmaf(a3, wv.y, acc[3][1]);
    acc[3][2] = fmaf(a3, wv.z, acc[3][2]);
    acc[3][3] = fmaf(a3, wv.w, acc[3][3]);
  }
  float4 bv = make_float4(0.f, 0.f, 0.f, 0.f);
  if (bias) bv = *(const float4*)(bias + c0);
#pragma unroll
  for (int i = 0; i < 4; ++i) {
    int n = nb + n0 + i;
    if (n < N) {
      float4 o;
      o.x = acc[i][0] + bv.x;
      o.y = acc[i][1] + bv.y;
      o.z = acc[i][2] + bv.z;
      o.w = acc[i][3] + bv.w;
      *(float4*)(C + (size_t)n * P + c0) = o;
    }
  }
}

// One edge per wave. x = current node features (N x 128), pq = [p|q] (N x 128).
__global__ void __launch_bounds__(256) k_edge(const float* __restrict__ x,
    const float* __restrict__ pq, const float* __restrict__ w2,
    const float* __restrict__ bias1, const float* __restrict__ bias2,
    const int* __restrict__ eidx, float* __restrict__ agg, int E) {
  int wave = threadIdx.x >> 6;
  int lane = threadIdx.x & 63;
  int e = blockIdx.x * 4 + wave;
  if (e >= E) return;
  int row = eidx[e];
  int col = eidx[E + e];

  // ---- phase 1: h[lane] = relu(p[row][lane] + q[col][lane] + b1[lane])
  float hv = pq[(size_t)row * 128 + lane] + pq[(size_t)col * 128 + 64 + lane] +
             bias1[lane];
  hv = fmaxf(hv, 0.f);

  // ---- phase 2: maps[o] = sum_m h[m]*w2[m][o] + b2[o]  (o = 0..31)
  // lanes 0..31 sum m=0..31; lanes 32..63 sum m=32..63; then combine halves.
  int half = lane >> 5, o32 = lane & 31;
  float part = 0.f;
#pragma unroll
  for (int m = 0; m < 32; ++m) {
    int mm = m + (half << 5);
    float hm = __shfl(hv, mm);
    part = fmaf(hm, w2[mm * 32 + o32], part);
  }
  float mapsv = part + __shfl(part, lane ^ 32) + bias2[o32];
  // mapsv: lane l and l+32 both hold maps[l&31]. Flat o = m16*16 + a*4 + b.

  // ---- phase 3: A = maps - maps^T ; T = expm(A/2^s) then square s times.
  // lanes 0..15: matrix 0 (f_u), lanes 16..31: matrix 1 (f_v).
  int base = lane & 48;
  int a = (lane >> 2) & 3, b = lane & 3;
  float Av = mapsv - __shfl(mapsv, base + b * 4 + a);
  float nrm = fabsf(Av);
  nrm = fmaxf(nrm, __shfl_xor(nrm, 1));
  nrm = fmaxf(nrm, __shfl_xor(nrm, 2));
  nrm = fmaxf(nrm, __shfl_xor(nrm, 4));
  nrm = fmaxf(nrm, __shfl_xor(nrm, 8));
  int ex = 0;
  (void)frexpf(8.f * nrm, &ex);  // s >= log2(8*nrm) => ||A/2^s||_1 <= 0.5
  int s = (nrm > 0.f) ? ex : 0;
  s = (s < 0) ? 0 : ((s > 30) ? 30 : s);
  if (lane >= 32) s = 0;  // lanes 32..63 carry garbage; keep smax clean
  float As = ldexpf(Av, -s);
  const float id = (a == b) ? 1.f : 0.f;
  float T = id;
#pragma unroll
  for (int k = 8; k >= 1; --k) {  // Horner: T = I + (A@T)/k
    float acc = 0.f;
#pragma unroll
    for (int c = 0; c < 4; ++c)
      acc = fmaf(__shfl(As, base + a * 4 + c), __shfl(T, base + c * 4 + b),
                 acc);
    T = fmaf(acc, 1.f / (float)k, id);
  }
  int smax = s;
  smax = max(smax, __shfl_xor(smax, 1));
  smax = max(smax, __shfl_xor(smax, 2));
  smax = max(smax, __shfl_xor(smax, 4));
  smax = max(smax, __shfl_xor(smax, 8));
  smax = max(smax, __shfl_xor(smax, 16));
  smax = max(smax, __shfl_xor(smax, 32));
  for (int it = 0; it < smax; ++it) {
    float acc = 0.f;
#pragma unroll
    for (int c = 0; c < 4; ++c)
      acc = fmaf(__shfl(T, base + a * 4 + c), __shfl(T, base + c * 4 + b), acc);
    T = (it < s) ? acc : T;
  }

  // ---- phase 4: M1 = Fu^T Fu (lanes 0..15), M2 = Fu^T Fv (lanes 16..31)
  int l4 = lane & 15, a2 = l4 >> 2, b2i = l4 & 3;
  int hsel = (lane >> 4) & 1;
  float Mv = 0.f;
#pragma unroll
  for (int c = 0; c < 4; ++c)
    Mv = fmaf(__shfl(T, c * 4 + a2), __shfl(T, hsel * 16 + c * 4 + b2i), Mv);

  // ---- phase 5: msg[o] = M1[a]·x_col[k] - M2[a]·x_row[k]; o=lane, lane+64
  int a5 = lane & 3, kb = lane & ~3;
  const float* xc = x + (size_t)col * 128 + kb;
  const float* xr = x + (size_t)row * 128 + kb;
  float4 xc1 = *(const float4*)xc;
  float4 xc2 = *(const float4*)(xc + 64);
  float4 xr1 = *(const float4*)xr;
  float4 xr2 = *(const float4*)(xr + 64);
  float m1r[4], m2r[4];
#pragma unroll
  for (int c = 0; c < 4; ++c) {
    m1r[c] = __shfl(Mv, a5 * 4 + c);
    m2r[c] = __shfl(Mv, 16 + a5 * 4 + c);
  }
  float msg1 = m1r[0] * xc1.x + m1r[1] * xc1.y + m1r[2] * xc1.z +
               m1r[3] * xc1.w -
               (m2r[0] * xr1.x + m2r[1] * xr1.y + m2r[2] * xr1.z +
                m2r[3] * xr1.w);
  float msg2 = m1r[0] * xc2.x + m1r[1] * xc2.y + m1r[2] * xc2.z +
               m1r[3] * xc2.w -
               (m2r[0] * xr2.x + m2r[1] * xr2.y + m2r[2] * xr2.z +
                m2r[3] * xr2.w);
  atomicAdd(agg + (size_t)col * 128 + lane, msg1);
  atomicAdd(agg + (size_t)col * 128 + 64 + lane, msg2);
}

__global__ void __launch_bounds__(256) k_node_elu(float* __restrict__ h,
    const float* __restrict__ agg, const float* __restrict__ epsp, int n4) {
  int i = blockIdx.x * 256 + threadIdx.x;
  if (i >= n4) return;
  float eps = *epsp;
  float4 v = ((const float4*)h)[i];
  float4 g = ((const float4*)agg)[i];
  float4 r;
  r.x = v.x - eps * g.x;
  r.y = v.y - eps * g.y;
  r.z = v.z - eps * g.z;
  r.w = v.w - eps * g.w;
  r.x = (r.x > 0.f) ? r.x : expm1f(r.x);
  r.y = (r.y > 0.f) ? r.y : expm1f(r.y);
  r.z = (r.z > 0.f) ? r.z : expm1f(r.z);
  r.w = (r.w > 0.f) ? r.w : expm1f(r.w);
  ((float4*)h)[i] = r;
}

extern "C" void kernel_launch(void* const* d_in, const int* in_sizes, int n_in,
                              void* d_out, int out_size, void* d_ws,
                              size_t ws_size, hipStream_t stream) {
  const float* x = (const float*)d_in[0];
  const int* eidx = (const int*)d_in[1];
  const float* lin_in_w = (const float*)d_in[2];
  const float* lin_in_b = (const float*)d_in[3];
  const float* c0w1 = (const float*)d_in[4];
  const float* c0b1 = (const float*)d_in[5];
  const float* c0w2 = (const float*)d_in[6];
  const float* c0b2 = (const float*)d_in[7];
  const float* c0eps = (const float*)d_in[8];
  const float* c1w1 = (const float*)d_in[9];
  const float* c1b1 = (const float*)d_in[10];
  const float* c1w2 = (const float*)d_in[11];
  const float* c1b2 = (const float*)d_in[12];
  const float* c1eps = (const float*)d_in[13];
  const float* lout_w = (const float*)d_in[14];
  const float* lout_b = (const float*)d_in[15];
  float* out = (float*)d_out;

  int N = in_sizes[0] / 128;
  int E = in_sizes[1] / 2;

  char* ws = (char*)d_ws;
  size_t szH = (size_t)N * 128 * sizeof(float);
  float* H = (float*)ws;
  float* PQ = (float*)(ws + szH);
  float* AGG = (float*)(ws + 2 * szH);
  float* WP = (float*)(ws + 3 * szH);

  dim3 blk(256);
  int gN = (N + 63) / 64;

  // h0 = x @ lin_in_w + lin_in_b
  k_gemm128<<<dim3(gN, 2), blk, 0, stream>>>(x, lin_in_w, lin_in_b, H, N, 128);

  for (int layer = 0; layer < 2; ++layer) {
    const float* w1 = layer ? c1w1 : c0w1;
    const float* b1 = layer ? c1b1 : c0b1;
    const float* w2 = layer ? c1w2 : c0w2;
    const float* b2 = layer ? c1b2 : c0b2;
    const float* ep = layer ? c1eps : c0eps;
    k_pack_w1<<<64, blk, 0, stream>>>(w1, WP);
    k_gemm128<<<dim3(gN, 2), blk, 0, stream>>>(H, WP, nullptr, PQ, N, 128);
    hipMemsetAsync(AGG, 0, szH, stream);
    k_edge<<<(E + 3) / 4, blk, 0, stream>>>(H, PQ, w2, b1, b2, eidx, AGG, E);
    int n4 = N * 32;  // N*128/4
    k_node_elu<<<(n4 + 255) / 256, blk, 0, stream>>>(H, AGG, ep, n4);
  }

  // out = h @ lin_out_w + lin_out_b
  k_gemm128<<<dim3(gN, 1), blk, 0, stream>>>(H, lout_w, lout_b, out, N, 64);
}

// Round 3
// 629.873 us; speedup vs baseline: 1.5826x; 1.5826x over previous
//
#include <hip/hip_runtime.h>
#include <math.h>

// ---------------------------------------------------------------------------
// SheafGNN forward, fp32.
// h0 = x@Win+b; 2x [pq = h@W1p; maps = relu(p[row]+q[col]+b1)@w2+b2 (k_maps);
//                   M1,M2 = expm-products per edge (k_expm, in-place);
//                   msg scatter-add (k_msg); h = elu(h - eps*agg)]; out GEMM.
// Round-2 post-mortem: one-edge-per-wave shuffle kernel was LDS-pipe bound
// (~134 ds_bpermute/edge ~= 420us predicted, 466us measured; VALUBusy 44%,
// HBM 10%). This version has ZERO shuffles: per-edge 4x4 algebra is
// one-edge-per-LANE in registers; h@w2 is a fused gather-GEMM with w2 read
// at wave-uniform addresses (s_load path).
// ---------------------------------------------------------------------------

__global__ void __launch_bounds__(256) k_pack_w1(const float* __restrict__ w1,
                                                 float* __restrict__ Wp) {
  int t = blockIdx.x * 256 + threadIdx.x;
  if (t >= 128 * 128) return;
  int i = t >> 7, o = t & 127;
  Wp[t] = (o < 64) ? w1[i * 64 + o] : w1[(128 + i) * 64 + (o - 64)];
}

// C(N x P) = A(N x 128) @ W(128 x P) + bias; P is 64 or 128, tile 64x64.
__global__ void __launch_bounds__(256) k_gemm128(const float* __restrict__ A,
    const float* __restrict__ W, const float* __restrict__ bias,
    float* __restrict__ C, int N, int P) {
  __shared__ float As[128 * 65];
  int t = threadIdx.x;
  int nb = blockIdx.x << 6, cb = blockIdx.y << 6;
#pragma unroll
  for (int i = 0; i < 32; ++i) {
    int idx = (i << 8) + t;
    int node = idx >> 7, k = idx & 127;
    float v = 0.f;
    if (nb + node < N) v = A[(size_t)(nb + node) * 128 + k];
    As[k * 65 + node] = v;
  }
  __syncthreads();
  int tx = t & 15, ty = t >> 4;
  int c0 = cb + (tx << 2);
  int n0 = ty << 2;
  float acc[4][4] = {};
  for (int k = 0; k < 128; ++k) {
    float4 wv = *(const float4*)(W + (size_t)k * P + c0);
    float a0 = As[k * 65 + n0 + 0];
    float a1 = As[k * 65 + n0 + 1];
    float a2 = As[k * 65 + n0 + 2];
    float a3 = As[k * 65 + n0 + 3];
    acc[0][0] = fmaf(a0, wv.x, acc[0][0]);
    acc[0][1] = fmaf(a0, wv.y, acc[0][1]);
    acc[0][2] = fmaf(a0, wv.z, acc[0][2]);
    acc[0][3] = fmaf(a0, wv.w, acc[0][3]);
    acc[1][0] = fmaf(a1, wv.x, acc[1][0]);
    acc[1][1] = fmaf(a1, wv.y, acc[1][1]);
    acc[1][2] = fmaf(a1, wv.z, acc[1][2]);
    acc[1][3] = fmaf(a1, wv.w, acc[1][3]);
    acc[2][0] = fmaf(a2, wv.x, acc[2][0]);
    acc[2][1] = fmaf(a2, wv.y, acc[2][1]);
    acc[2][2] = fmaf(a2, wv.z, acc[2][2]);
    acc[2][3] = fmaf(a2, wv.w, acc[2][3]);
    acc[3][0] = fmaf(a3, wv.x, acc[3][0]);
    acc[3][1] = fmaf(a3, wv.y, acc[3][1]);
    acc[3][2] = fmaf(a3, wv.z, acc[3][2]);
    acc[3][3] = fmaf(a3, wv.w, acc[3][3]);
  }
  float4 bv = make_float4(0.f, 0.f, 0.f, 0.f);
  if (bias) bv = *(const float4*)(bias + c0);
#pragma unroll
  for (int i = 0; i < 4; ++i) {
    int n = nb + n0 + i;
    if (n < N) {
      float4 o;
      o.x = acc[i][0] + bv.x;
      o.y = acc[i][1] + bv.y;
      o.z = acc[i][2] + bv.z;
      o.w = acc[i][3] + bv.w;
      *(float4*)(C + (size_t)n * P + c0) = o;
    }
  }
}

// maps[e][0:32] = relu(p[row]+q[col]+b1) @ w2 + b2. 256 edges/block,
// gather staged transposed in LDS; compute is thread-per-edge with
// wave-uniform (scalar) w2/b2 access.
__global__ void __launch_bounds__(256) k_maps(const float* __restrict__ pq,
    const float* __restrict__ w2, const float* __restrict__ b1,
    const float* __restrict__ b2, const int* __restrict__ eidx,
    float* __restrict__ maps, int E) {
  __shared__ float Hst[64 * 261];  // [m][edge], stride 261: conflict-free
  __shared__ int Rs[256], Cs[256];
  int t = threadIdx.x;
  int e0 = blockIdx.x * 256;
  {
    int e = e0 + t;
    Rs[t] = (e < E) ? eidx[e] : 0;
    Cs[t] = (e < E) ? eidx[E + e] : 0;
  }
  __syncthreads();
  int lane = t & 63;
  float bc = b1[lane];
#pragma unroll
  for (int i = 0; i < 64; ++i) {
    int ei = i * 4 + (t >> 6);  // wave-uniform edge, lane = feature
    float v = pq[(size_t)Rs[ei] * 128 + lane] +
              pq[(size_t)Cs[ei] * 128 + 64 + lane] + bc;
    Hst[lane * 261 + ei] = fmaxf(v, 0.f);
  }
  __syncthreads();
  float acc[32];
#pragma unroll
  for (int o = 0; o < 32; ++o) acc[o] = b2[o];  // uniform -> s_load
  for (int m = 0; m < 64; ++m) {
    float hm = Hst[m * 261 + t];  // stride-1 across lanes
#pragma unroll
    for (int o = 0; o < 32; ++o)
      acc[o] = fmaf(hm, w2[m * 32 + o], acc[o]);  // uniform -> s_load
  }
  int e = e0 + t;
  if (e < E) {
    float* mp = maps + (size_t)e * 32;
#pragma unroll
    for (int i = 0; i < 8; ++i) {
      float4 v = make_float4(acc[i * 4], acc[i * 4 + 1], acc[i * 4 + 2],
                             acc[i * 4 + 3]);
      *(float4*)(mp + i * 4) = v;
    }
  }
}

// expm of antisym(4x4) via scaling-squaring + Taylor(8), all in registers.
__device__ __forceinline__ void expm4(const float* __restrict__ Min,
                                      float* __restrict__ T) {
  float A[16];
#pragma unroll
  for (int a = 0; a < 4; ++a)
#pragma unroll
    for (int b = 0; b < 4; ++b) A[a * 4 + b] = Min[a * 4 + b] - Min[b * 4 + a];
  float nrm = 0.f;
#pragma unroll
  for (int i = 0; i < 16; ++i) nrm = fmaxf(nrm, fabsf(A[i]));
  int ex = 0;
  (void)frexpf(8.f * nrm, &ex);  // maxabs/2^s <= 1/8 -> ||A/2^s||_inf <= 0.5
  int s = (nrm > 0.f) ? ((ex < 0) ? 0 : ex) : 0;
  s = (s > 30) ? 30 : s;
  float sc = ldexpf(1.f, -s);
#pragma unroll
  for (int i = 0; i < 16; ++i) A[i] *= sc;
#pragma unroll
  for (int i = 0; i < 16; ++i) T[i] = ((i & 3) == (i >> 2)) ? 1.f : 0.f;
  float P[16];
#pragma unroll
  for (int k = 8; k >= 1; --k) {  // Horner: T = I + (A@T)/k
#pragma unroll
    for (int a = 0; a < 4; ++a)
#pragma unroll
      for (int b = 0; b < 4; ++b) {
        float acc = 0.f;
#pragma unroll
        for (int c = 0; c < 4; ++c) acc = fmaf(A[a * 4 + c], T[c * 4 + b], acc);
        P[a * 4 + b] = acc;
      }
    float rk = 1.f / (float)k;
#pragma unroll
    for (int i = 0; i < 16; ++i)
      T[i] = fmaf(P[i], rk, ((i & 3) == (i >> 2)) ? 1.f : 0.f);
  }
  for (int it = 0; it < s; ++it) {  // divergent but tiny
#pragma unroll
    for (int a = 0; a < 4; ++a)
#pragma unroll
      for (int b = 0; b < 4; ++b) {
        float acc = 0.f;
#pragma unroll
        for (int c = 0; c < 4; ++c) acc = fmaf(T[a * 4 + c], T[c * 4 + b], acc);
        P[a * 4 + b] = acc;
      }
#pragma unroll
    for (int i = 0; i < 16; ++i) T[i] = P[i];
  }
}

// One edge per LANE: maps[e][0:32] -> in-place [M1 | M2],
// M1 = Fu^T Fu, M2 = Fu^T Fv.
__global__ void __launch_bounds__(256) k_expm(float* __restrict__ maps, int E) {
  int e = blockIdx.x * 256 + threadIdx.x;
  if (e >= E) return;
  float* mp = maps + (size_t)e * 32;
  float M[32];
#pragma unroll
  for (int i = 0; i < 8; ++i) *(float4*)(M + i * 4) = *(const float4*)(mp + i * 4);
  float Fu[16], Fv[16];
  expm4(M, Fu);
  expm4(M + 16, Fv);
  float out[32];
#pragma unroll
  for (int a = 0; a < 4; ++a)
#pragma unroll
    for (int b = 0; b < 4; ++b) {
      float s1 = 0.f, s2 = 0.f;
#pragma unroll
      for (int c = 0; c < 4; ++c) {
        s1 = fmaf(Fu[c * 4 + a], Fu[c * 4 + b], s1);
        s2 = fmaf(Fu[c * 4 + a], Fv[c * 4 + b], s2);
      }
      out[a * 4 + b] = s1;
      out[16 + a * 4 + b] = s2;
    }
#pragma unroll
  for (int i = 0; i < 8; ++i) {
    float4 v = make_float4(out[i * 4], out[i * 4 + 1], out[i * 4 + 2],
                           out[i * 4 + 3]);
    *(float4*)(mp + i * 4) = v;
  }
}

// One edge per wave; lane o computes msg[o], msg[o+64]; no shuffles.
__global__ void __launch_bounds__(256) k_msg(const float* __restrict__ x,
    const float* __restrict__ MM, const int* __restrict__ eidx,
    float* __restrict__ agg, int E) {
  int wave = threadIdx.x >> 6;
  int lane = threadIdx.x & 63;
  int e = blockIdx.x * 4 + wave;
  if (e >= E) return;
  int row = eidx[e];
  int col = eidx[E + e];
  int a5 = lane & 3, kb = lane & ~3;
  const float* mp = MM + (size_t)e * 32;
  float4 m1 = *(const float4*)(mp + a5 * 4);        // M1[a][:]
  float4 m2 = *(const float4*)(mp + 16 + a5 * 4);   // M2[a][:]
  const float* xc = x + (size_t)col * 128 + kb;
  const float* xr = x + (size_t)row * 128 + kb;
  float4 xc1 = *(const float4*)xc;
  float4 xc2 = *(const float4*)(xc + 64);
  float4 xr1 = *(const float4*)xr;
  float4 xr2 = *(const float4*)(xr + 64);
  float msg1 = m1.x * xc1.x + m1.y * xc1.y + m1.z * xc1.z + m1.w * xc1.w -
               (m2.x * xr1.x + m2.y * xr1.y + m2.z * xr1.z + m2.w * xr1.w);
  float msg2 = m1.x * xc2.x + m1.y * xc2.y + m1.z * xc2.z + m1.w * xc2.w -
               (m2.x * xr2.x + m2.y * xr2.y + m2.z * xr2.z + m2.w * xr2.w);
  atomicAdd(agg + (size_t)col * 128 + lane, msg1);
  atomicAdd(agg + (size_t)col * 128 + 64 + lane, msg2);
}

__global__ void __launch_bounds__(256) k_node_elu(float* __restrict__ h,
    const float* __restrict__ agg, const float* __restrict__ epsp, int n4) {
  int i = blockIdx.x * 256 + threadIdx.x;
  if (i >= n4) return;
  float eps = *epsp;
  float4 v = ((const float4*)h)[i];
  float4 g = ((const float4*)agg)[i];
  float4 r;
  r.x = v.x - eps * g.x;
  r.y = v.y - eps * g.y;
  r.z = v.z - eps * g.z;
  r.w = v.w - eps * g.w;
  r.x = (r.x > 0.f) ? r.x : expm1f(r.x);
  r.y = (r.y > 0.f) ? r.y : expm1f(r.y);
  r.z = (r.z > 0.f) ? r.z : expm1f(r.z);
  r.w = (r.w > 0.f) ? r.w : expm1f(r.w);
  ((float4*)h)[i] = r;
}

extern "C" void kernel_launch(void* const* d_in, const int* in_sizes, int n_in,
                              void* d_out, int out_size, void* d_ws,
                              size_t ws_size, hipStream_t stream) {
  const float* x = (const float*)d_in[0];
  const int* eidx = (const int*)d_in[1];
  const float* lin_in_w = (const float*)d_in[2];
  const float* lin_in_b = (const float*)d_in[3];
  const float* c0w1 = (const float*)d_in[4];
  const float* c0b1 = (const float*)d_in[5];
  const float* c0w2 = (const float*)d_in[6];
  const float* c0b2 = (const float*)d_in[7];
  const float* c0eps = (const float*)d_in[8];
  const float* c1w1 = (const float*)d_in[9];
  const float* c1b1 = (const float*)d_in[10];
  const float* c1w2 = (const float*)d_in[11];
  const float* c1b2 = (const float*)d_in[12];
  const float* c1eps = (const float*)d_in[13];
  const float* lout_w = (const float*)d_in[14];
  const float* lout_b = (const float*)d_in[15];
  float* out = (float*)d_out;

  int N = in_sizes[0] / 128;
  int E = in_sizes[1] / 2;

  char* ws = (char*)d_ws;
  size_t szH = (size_t)N * 128 * sizeof(float);
  float* H = (float*)ws;
  float* PQ = (float*)(ws + szH);
  float* AGG = (float*)(ws + 2 * szH);
  float* WP = (float*)(ws + 3 * szH);
  float* MAPS = (float*)(ws + 3 * szH + (1 << 20));  // E*32 floats (~41 MB)

  dim3 blk(256);
  int gN = (N + 63) / 64;

  k_gemm128<<<dim3(gN, 2), blk, 0, stream>>>(x, lin_in_w, lin_in_b, H, N, 128);

  for (int layer = 0; layer < 2; ++layer) {
    const float* w1 = layer ? c1w1 : c0w1;
    const float* b1 = layer ? c1b1 : c0b1;
    const float* w2 = layer ? c1w2 : c0w2;
    const float* b2 = layer ? c1b2 : c0b2;
    const float* ep = layer ? c1eps : c0eps;
    k_pack_w1<<<64, blk, 0, stream>>>(w1, WP);
    k_gemm128<<<dim3(gN, 2), blk, 0, stream>>>(H, WP, nullptr, PQ, N, 128);
    hipMemsetAsync(AGG, 0, szH, stream);
    k_maps<<<(E + 255) / 256, blk, 0, stream>>>(PQ, w2, b1, b2, eidx, MAPS, E);
    k_expm<<<(E + 255) / 256, blk, 0, stream>>>(MAPS, E);
    k_msg<<<(E + 3) / 4, blk, 0, stream>>>(H, MAPS, eidx, AGG, E);
    int n4 = N * 32;
    k_node_elu<<<(n4 + 255) / 256, blk, 0, stream>>>(H, AGG, ep, n4);
  }

  k_gemm128<<<dim3(gN, 1), blk, 0, stream>>>(H, lout_w, lout_b, out, N, 64);
}

// Round 4
// 489.307 us; speedup vs baseline: 2.0372x; 1.2873x over previous
//
#include <hip/hip_runtime.h>
#include <math.h>

// ---------------------------------------------------------------------------
// SheafGNN forward, fp32.
// Once:  CSR-by-col build (hist/scan/fill -> ptr, adjrow, perm).
// h0 = x@Win+b; 2x [pq = h@W1p; k_maps_expm: maps=relu(p[row]+q[col]+b1)@w2+b2
//   -> expm -> M1,M2 written at CSR slot perm[e]; k_agg: per-node wave reads
//   its CSR segment, acc msg in regs, fused h=elu(h-eps*agg) -> ping-pong];
// out = h@Wout+b.
// R3 post-mortem: k_msg was atomic-RMW bound (41M atomicAdds/layer,
// WRITE_SIZE==atomic bytes exactly; VALU 17%, HBM 29%). CSR removes them.
// k_maps was gather/LDS-heavy; now float4 gather + fused expm.
// ---------------------------------------------------------------------------

__global__ void __launch_bounds__(256) k_pack_w1(const float* __restrict__ w1,
                                                 float* __restrict__ Wp) {
  int t = blockIdx.x * 256 + threadIdx.x;
  if (t >= 128 * 128) return;
  int i = t >> 7, o = t & 127;
  Wp[t] = (o < 64) ? w1[i * 64 + o] : w1[(128 + i) * 64 + (o - 64)];
}

// C(N x P) = A(N x 128) @ W(128 x P) + bias; P is 64 or 128, tile 64x64.
__global__ void __launch_bounds__(256) k_gemm128(const float* __restrict__ A,
    const float* __restrict__ W, const float* __restrict__ bias,
    float* __restrict__ C, int N, int P) {
  __shared__ float As[128 * 65];
  int t = threadIdx.x;
  int nb = blockIdx.x << 6, cb = blockIdx.y << 6;
#pragma unroll
  for (int i = 0; i < 32; ++i) {
    int idx = (i << 8) + t;
    int node = idx >> 7, k = idx & 127;
    float v = 0.f;
    if (nb + node < N) v = A[(size_t)(nb + node) * 128 + k];
    As[k * 65 + node] = v;
  }
  __syncthreads();
  int tx = t & 15, ty = t >> 4;
  int c0 = cb + (tx << 2);
  int n0 = ty << 2;
  float acc[4][4] = {};
  for (int k = 0; k < 128; ++k) {
    float4 wv = *(const float4*)(W + (size_t)k * P + c0);
    float a0 = As[k * 65 + n0 + 0];
    float a1 = As[k * 65 + n0 + 1];
    float a2 = As[k * 65 + n0 + 2];
    float a3 = As[k * 65 + n0 + 3];
    acc[0][0] = fmaf(a0, wv.x, acc[0][0]);
    acc[0][1] = fmaf(a0, wv.y, acc[0][1]);
    acc[0][2] = fmaf(a0, wv.z, acc[0][2]);
    acc[0][3] = fmaf(a0, wv.w, acc[0][3]);
    acc[1][0] = fmaf(a1, wv.x, acc[1][0]);
    acc[1][1] = fmaf(a1, wv.y, acc[1][1]);
    acc[1][2] = fmaf(a1, wv.z, acc[1][2]);
    acc[1][3] = fmaf(a1, wv.w, acc[1][3]);
    acc[2][0] = fmaf(a2, wv.x, acc[2][0]);
    acc[2][1] = fmaf(a2, wv.y, acc[2][1]);
    acc[2][2] = fmaf(a2, wv.z, acc[2][2]);
    acc[2][3] = fmaf(a2, wv.w, acc[2][3]);
    acc[3][0] = fmaf(a3, wv.x, acc[3][0]);
    acc[3][1] = fmaf(a3, wv.y, acc[3][1]);
    acc[3][2] = fmaf(a3, wv.z, acc[3][2]);
    acc[3][3] = fmaf(a3, wv.w, acc[3][3]);
  }
  float4 bv = make_float4(0.f, 0.f, 0.f, 0.f);
  if (bias) bv = *(const float4*)(bias + c0);
#pragma unroll
  for (int i = 0; i < 4; ++i) {
    int n = nb + n0 + i;
    if (n < N) {
      float4 o;
      o.x = acc[i][0] + bv.x;
      o.y = acc[i][1] + bv.y;
      o.z = acc[i][2] + bv.z;
      o.w = acc[i][3] + bv.w;
      *(float4*)(C + (size_t)n * P + c0) = o;
    }
  }
}

// ---- CSR build (by col) ----------------------------------------------------
__global__ void __launch_bounds__(256) k_hist(const int* __restrict__ eidx,
                                              int* __restrict__ cnt, int E) {
  int e = blockIdx.x * 256 + threadIdx.x;
  if (e < E) atomicAdd(&cnt[eidx[E + e]], 1);
}

__global__ void __launch_bounds__(256) k_scan(const int* __restrict__ cnt,
    int* __restrict__ ptr, int* __restrict__ cursor, int N) {
  __shared__ int sums[256];
  int t = threadIdx.x;
  int chunk = (N + 255) / 256;
  int lo = t * chunk;
  int hi = lo + chunk;
  if (hi > N) hi = N;
  if (lo > N) lo = N;
  int s = 0;
  for (int i = lo; i < hi; ++i) s += cnt[i];
  sums[t] = s;
  __syncthreads();
  for (int d = 1; d < 256; d <<= 1) {
    int v = (t >= d) ? sums[t - d] : 0;
    __syncthreads();
    sums[t] += v;
    __syncthreads();
  }
  int run = (t == 0) ? 0 : sums[t - 1];
  for (int i = lo; i < hi; ++i) {
    ptr[i] = run;
    cursor[i] = run;
    run += cnt[i];
  }
  if (t == 255) ptr[N] = run;
}

__global__ void __launch_bounds__(256) k_fill(const int* __restrict__ eidx,
    int* __restrict__ cursor, int* __restrict__ adjrow, int* __restrict__ perm,
    int E) {
  int e = blockIdx.x * 256 + threadIdx.x;
  if (e >= E) return;
  int r = eidx[e], c = eidx[E + e];
  int pos = atomicAdd(&cursor[c], 1);
  adjrow[pos] = r;
  perm[e] = pos;
}

// ---- fused edge MLP tail + expm + M-products -------------------------------
__device__ __forceinline__ void expm4(const float* __restrict__ Min,
                                      float* __restrict__ T) {
  float A[16];
#pragma unroll
  for (int a = 0; a < 4; ++a)
#pragma unroll
    for (int b = 0; b < 4; ++b) A[a * 4 + b] = Min[a * 4 + b] - Min[b * 4 + a];
  float nrm = 0.f;
#pragma unroll
  for (int i = 0; i < 16; ++i) nrm = fmaxf(nrm, fabsf(A[i]));
  int ex = 0;
  (void)frexpf(8.f * nrm, &ex);  // maxabs/2^s <= 1/8
  int s = (nrm > 0.f) ? ((ex < 0) ? 0 : ex) : 0;
  s = (s > 30) ? 30 : s;
  float sc = ldexpf(1.f, -s);
#pragma unroll
  for (int i = 0; i < 16; ++i) A[i] *= sc;
#pragma unroll
  for (int i = 0; i < 16; ++i) T[i] = ((i & 3) == (i >> 2)) ? 1.f : 0.f;
  float P[16];
#pragma unroll
  for (int k = 8; k >= 1; --k) {  // Horner: T = I + (A@T)/k
#pragma unroll
    for (int a = 0; a < 4; ++a)
#pragma unroll
      for (int b = 0; b < 4; ++b) {
        float acc = 0.f;
#pragma unroll
        for (int c = 0; c < 4; ++c) acc = fmaf(A[a * 4 + c], T[c * 4 + b], acc);
        P[a * 4 + b] = acc;
      }
    float rk = 1.f / (float)k;
#pragma unroll
    for (int i = 0; i < 16; ++i)
      T[i] = fmaf(P[i], rk, ((i & 3) == (i >> 2)) ? 1.f : 0.f);
  }
  for (int it = 0; it < s; ++it) {
#pragma unroll
    for (int a = 0; a < 4; ++a)
#pragma unroll
      for (int b = 0; b < 4; ++b) {
        float acc = 0.f;
#pragma unroll
        for (int c = 0; c < 4; ++c) acc = fmaf(T[a * 4 + c], T[c * 4 + b], acc);
        P[a * 4 + b] = acc;
      }
#pragma unroll
    for (int i = 0; i < 16; ++i) T[i] = P[i];
  }
}

// 128 edges / 128-thread block. Gather float4s -> LDS [m][e] (stride 132,
// conflict-free); thread-per-edge h@w2 with wave-uniform w2 (s_load path);
// fused expm + M1/M2; write to CSR slot perm[e].
__global__ void __launch_bounds__(128) k_maps_expm(const float* __restrict__ pq,
    const float* __restrict__ w2, const float* __restrict__ b1,
    const float* __restrict__ b2, const int* __restrict__ eidx,
    const int* __restrict__ perm, float* __restrict__ MM, int E) {
  __shared__ float Hst[64 * 132];
  int t = threadIdx.x;
  int w = t >> 6, lane = t & 63;
  int e0 = blockIdx.x * 128;
  int esub = lane >> 2, c4 = lane & 3;
#pragma unroll
  for (int i = 0; i < 4; ++i) {
    int eloc = w * 64 + i * 16 + esub;
    int e = e0 + eloc;
    int es = (e < E) ? e : (E - 1);
    int row = eidx[es], col = eidx[E + es];
#pragma unroll
    for (int j = 0; j < 4; ++j) {
      int c = j * 4 + c4;  // feature-quad 0..15
      float4 pv = *(const float4*)(pq + (size_t)row * 128 + c * 4);
      float4 qv = *(const float4*)(pq + (size_t)col * 128 + 64 + c * 4);
      float4 bv = *(const float4*)(b1 + c * 4);
      Hst[(c * 4 + 0) * 132 + eloc] = fmaxf(pv.x + qv.x + bv.x, 0.f);
      Hst[(c * 4 + 1) * 132 + eloc] = fmaxf(pv.y + qv.y + bv.y, 0.f);
      Hst[(c * 4 + 2) * 132 + eloc] = fmaxf(pv.z + qv.z + bv.z, 0.f);
      Hst[(c * 4 + 3) * 132 + eloc] = fmaxf(pv.w + qv.w + bv.w, 0.f);
    }
  }
  __syncthreads();
  float acc[32];
#pragma unroll
  for (int o = 0; o < 32; ++o) acc[o] = b2[o];  // uniform -> s_load
  for (int m = 0; m < 64; ++m) {
    float hm = Hst[m * 132 + t];  // stride-1 across lanes
#pragma unroll
    for (int o = 0; o < 32; ++o)
      acc[o] = fmaf(hm, w2[m * 32 + o], acc[o]);  // uniform -> s_load
  }
  int e = e0 + t;
  if (e >= E) return;
  float Fu[16], Fv[16];
  expm4(acc, Fu);
  expm4(acc + 16, Fv);
  float out[32];
#pragma unroll
  for (int a = 0; a < 4; ++a)
#pragma unroll
    for (int b = 0; b < 4; ++b) {
      float s1 = 0.f, s2 = 0.f;
#pragma unroll
      for (int c = 0; c < 4; ++c) {
        s1 = fmaf(Fu[c * 4 + a], Fu[c * 4 + b], s1);  // (Fu^T Fu)[a,b]
        s2 = fmaf(Fu[c * 4 + a], Fv[c * 4 + b], s2);  // (Fu^T Fv)[a,b]
      }
      out[a * 4 + b] = s1;
      out[16 + a * 4 + b] = s2;
    }
  float* mp = MM + (size_t)perm[e] * 32;
#pragma unroll
  for (int i = 0; i < 8; ++i) {
    float4 v = make_float4(out[i * 4], out[i * 4 + 1], out[i * 4 + 2],
                           out[i * 4 + 3]);
    *(float4*)(mp + i * 4) = v;
  }
}

// One wave per node: iterate CSR segment, acc msg in 2 regs/lane, fused
// h_out = elu(h - eps*agg). No atomics. x=cur features, xout=next buffer.
__global__ void __launch_bounds__(256) k_agg(const float* __restrict__ x,
    const float* __restrict__ MM, const int* __restrict__ ptr,
    const int* __restrict__ adjrow, const float* __restrict__ epsp,
    float* __restrict__ xout, int N) {
  int wv = threadIdx.x >> 6, lane = threadIdx.x & 63;
  int v = blockIdx.x * 4 + wv;
  if (v >= N) return;
  int p0 = ptr[v], p1 = ptr[v + 1];
  int a = lane & 3, kb = lane & ~3;
  const float* xv = x + (size_t)v * 128;
  float4 xi1 = *(const float4*)(xv + kb);
  float4 xi2 = *(const float4*)(xv + 64 + kb);
  float hv1 = xv[lane], hv2 = xv[64 + lane];
  float acc1 = 0.f, acc2 = 0.f;
  for (int j = p0; j < p1; ++j) {
    const float* mp = MM + (size_t)j * 32;  // contiguous in CSR order
    float4 m1 = *(const float4*)(mp + a * 4);
    float4 m2 = *(const float4*)(mp + 16 + a * 4);
    int r = adjrow[j];  // wave-uniform broadcast load
    const float* xr = x + (size_t)r * 128;
    float4 xr1 = *(const float4*)(xr + kb);
    float4 xr2 = *(const float4*)(xr + 64 + kb);
    acc1 += m1.x * xi1.x + m1.y * xi1.y + m1.z * xi1.z + m1.w * xi1.w -
            (m2.x * xr1.x + m2.y * xr1.y + m2.z * xr1.z + m2.w * xr1.w);
    acc2 += m1.x * xi2.x + m1.y * xi2.y + m1.z * xi2.z + m1.w * xi2.w -
            (m2.x * xr2.x + m2.y * xr2.y + m2.z * xr2.z + m2.w * xr2.w);
  }
  float eps = *epsp;
  float r1 = hv1 - eps * acc1;
  float r2 = hv2 - eps * acc2;
  r1 = (r1 > 0.f) ? r1 : expm1f(r1);
  r2 = (r2 > 0.f) ? r2 : expm1f(r2);
  xout[(size_t)v * 128 + lane] = r1;
  xout[(size_t)v * 128 + 64 + lane] = r2;
}

extern "C" void kernel_launch(void* const* d_in, const int* in_sizes, int n_in,
                              void* d_out, int out_size, void* d_ws,
                              size_t ws_size, hipStream_t stream) {
  const float* x = (const float*)d_in[0];
  const int* eidx = (const int*)d_in[1];
  const float* lin_in_w = (const float*)d_in[2];
  const float* lin_in_b = (const float*)d_in[3];
  const float* c0w1 = (const float*)d_in[4];
  const float* c0b1 = (const float*)d_in[5];
  const float* c0w2 = (const float*)d_in[6];
  const float* c0b2 = (const float*)d_in[7];
  const float* c0eps = (const float*)d_in[8];
  const float* c1w1 = (const float*)d_in[9];
  const float* c1b1 = (const float*)d_in[10];
  const float* c1w2 = (const float*)d_in[11];
  const float* c1b2 = (const float*)d_in[12];
  const float* c1eps = (const float*)d_in[13];
  const float* lout_w = (const float*)d_in[14];
  const float* lout_b = (const float*)d_in[15];
  float* out = (float*)d_out;

  int N = in_sizes[0] / 128;
  int E = in_sizes[1] / 2;

  char* ws = (char*)d_ws;
  size_t szH = (size_t)N * 128 * sizeof(float);
  float* H = (float*)ws;
  float* H2 = (float*)(ws + szH);
  float* PQ = (float*)(ws + 2 * szH);
  float* WP = (float*)(ws + 3 * szH);                    // 64 KB
  float* MAPS = (float*)(ws + 3 * szH + (1 << 20));      // E*32 floats
  char* ip = ws + 3 * szH + (1 << 20) + (size_t)E * 32 * sizeof(float);
  int* cnt = (int*)ip;                 // N
  int* ptr = (int*)(ip + 4 * (size_t)(N + 64));          // N+1
  int* cursor = (int*)(ip + 8 * (size_t)(N + 64));       // N
  int* adjrow = (int*)(ip + 12 * (size_t)(N + 64));      // E
  int* perm = (int*)(ip + 12 * (size_t)(N + 64) + 4 * (size_t)E);  // E

  dim3 blk(256);
  int gN = (N + 63) / 64;
  int gE = (E + 255) / 256;

  // CSR build (edge_index shared by both conv layers)
  hipMemsetAsync(cnt, 0, (size_t)N * 4, stream);
  k_hist<<<gE, blk, 0, stream>>>(eidx, cnt, E);
  k_scan<<<1, blk, 0, stream>>>(cnt, ptr, cursor, N);
  k_fill<<<gE, blk, 0, stream>>>(eidx, cursor, adjrow, perm, E);

  // h0 = x @ lin_in_w + lin_in_b
  k_gemm128<<<dim3(gN, 2), blk, 0, stream>>>(x, lin_in_w, lin_in_b, H, N, 128);

  float* cur = H;
  float* nxt = H2;
  for (int layer = 0; layer < 2; ++layer) {
    const float* w1 = layer ? c1w1 : c0w1;
    const float* b1 = layer ? c1b1 : c0b1;
    const float* w2 = layer ? c1w2 : c0w2;
    const float* b2 = layer ? c1b2 : c0b2;
    const float* ep = layer ? c1eps : c0eps;
    k_pack_w1<<<64, blk, 0, stream>>>(w1, WP);
    k_gemm128<<<dim3(gN, 2), blk, 0, stream>>>(cur, WP, nullptr, PQ, N, 128);
    k_maps_expm<<<(E + 127) / 128, dim3(128), 0, stream>>>(PQ, w2, b1, b2,
                                                           eidx, perm, MAPS, E);
    k_agg<<<(N + 3) / 4, blk, 0, stream>>>(cur, MAPS, ptr, adjrow, ep, nxt, N);
    float* tmp = cur;
    cur = nxt;
    nxt = tmp;
  }

  k_gemm128<<<dim3(gN, 1), blk, 0, stream>>>(cur, lout_w, lout_b, out, N, 64);
}